// Round 1
// baseline (7269.332 us; speedup 1.0000x reference)
//
#include <hip/hip_runtime.h>
#include <cstddef>

// Problem constants (match reference)
#define NUC 40000
#define NIC 60000
#define NC  100000   // NU + NI
#define DLC 256
#define DXC 64

__device__ __forceinline__ float lrelu(float x) { return x >= 0.f ? x : 0.01f * x; }

enum { EPI_NONE = 0, EPI_BIAS = 1, EPI_LIN = 2, EPI_G = 3 };

// C[M,Nc] = epi( op(A[M,K]) @ W[K,Nc] )
// EPI_NONE: acc
// EPI_BIAS: acc + bias[n]
// EPI_LIN : lrelu(acc + bias[n]) + extra[r*Nc+n]        (extra = id_embedding)
// EPI_G   : lrelu(acc + bias[n] + extra[r*Nc+n])        (extra = x_hat)
// LRELU_A : apply leaky-relu to A elements on load (for h = lrelu(segment_sum))
template<int EPI, bool LRELU_A>
__global__ __launch_bounds__(256)
void gemm_f32(const float* __restrict__ A, const float* __restrict__ W,
              const float* __restrict__ bias, const float* __restrict__ extra,
              float* __restrict__ C, int M, int K, int Nc)
{
    __shared__ float As[16][68];   // [k][m], padded to 68 (16B-aligned rows, conflict-light)
    __shared__ float Bs[16][68];   // [k][n]

    const int t    = threadIdx.x;
    const int row0 = blockIdx.x * 64;
    const int n0   = blockIdx.y * 64;
    const int tm   = t >> 4;       // 0..15, owns rows tm*4..tm*4+3
    const int tn   = t & 15;       // 0..15, owns cols tn*4..tn*4+3
    const int ak   = t & 15;       // A-load: k col
    const int am   = t >> 4;       // A-load: m row base (+16*i)
    const int bn   = t & 63;       // B-load: n col
    const int bk0  = t >> 6;       // B-load: k row base (+4*j)

    float acc[4][4] = {};

    for (int k0 = 0; k0 < K; k0 += 16) {
        #pragma unroll
        for (int i = 0; i < 4; ++i) {
            int m = am + 16 * i;
            int r = row0 + m;
            float v = (r < M) ? A[(size_t)r * K + k0 + ak] : 0.f;
            if constexpr (LRELU_A) v = lrelu(v);
            As[ak][m] = v;
        }
        #pragma unroll
        for (int j = 0; j < 4; ++j) {
            int k = bk0 + 4 * j;
            Bs[k][bn] = W[(size_t)(k0 + k) * Nc + n0 + bn];
        }
        __syncthreads();
        #pragma unroll
        for (int kk = 0; kk < 16; ++kk) {
            float4 a4 = *(const float4*)&As[kk][tm << 2];
            float4 b4 = *(const float4*)&Bs[kk][tn << 2];
            float av[4] = {a4.x, a4.y, a4.z, a4.w};
            float bv[4] = {b4.x, b4.y, b4.z, b4.w};
            #pragma unroll
            for (int i = 0; i < 4; ++i)
                #pragma unroll
                for (int j = 0; j < 4; ++j)
                    acc[i][j] = fmaf(av[i], bv[j], acc[i][j]);
        }
        __syncthreads();
    }

    #pragma unroll
    for (int i = 0; i < 4; ++i) {
        int r = row0 + (tm << 2) + i;
        if (r >= M) continue;
        float o[4];
        #pragma unroll
        for (int j = 0; j < 4; ++j) {
            int cn = n0 + (tn << 2) + j;
            float v = acc[i][j];
            if constexpr (EPI == EPI_BIAS) {
                v += bias[cn];
            } else if constexpr (EPI == EPI_LIN) {
                v = lrelu(v + bias[cn]) + extra[(size_t)r * Nc + cn];
            } else if constexpr (EPI == EPI_G) {
                v = lrelu(v + bias[cn] + extra[(size_t)r * Nc + cn]);
            }
            o[j] = v;
        }
        *(float4*)&C[(size_t)r * Nc + n0 + (tn << 2)] =
            make_float4(o[0], o[1], o[2], o[3]);
    }
}

// x[row] = (row < NU ? pref[row] : x[row]) / max(||.||2, 1e-12); DL=256, one wave per row
__global__ __launch_bounds__(256)
void build_norm_x(const float* __restrict__ pref, float* __restrict__ x, int nu, int n)
{
    int row  = blockIdx.x * 4 + (threadIdx.x >> 6);
    int lane = threadIdx.x & 63;
    if (row >= n) return;
    const float* srcp = (row < nu) ? (pref + (size_t)row * 256) : (x + (size_t)row * 256);
    float4 v = ((const float4*)srcp)[lane];
    float s = v.x * v.x + v.y * v.y + v.z * v.z + v.w * v.w;
    #pragma unroll
    for (int off = 32; off; off >>= 1) s += __shfl_xor(s, off);
    float scale = 1.f / fmaxf(sqrtf(s), 1e-12f);
    v.x *= scale; v.y *= scale; v.z *= scale; v.w *= scale;
    ((float4*)(x + (size_t)row * 256))[lane] = v;
}

// h[dst[e]] += m[src[e]], D = DQ*4 floats per row
template<int DQ>
__global__ __launch_bounds__(256)
void scatter_add(const float* __restrict__ m, const int* __restrict__ src,
                 const int* __restrict__ dst, float* __restrict__ h, int nE)
{
    int idx = blockIdx.x * 256 + threadIdx.x;
    if (idx >= nE * DQ) return;
    int e = idx / DQ, c = idx % DQ;
    int s = src[e], d = dst[e];
    const float4 v = *(const float4*)(m + (size_t)s * (DQ * 4) + c * 4);
    float* hp = h + (size_t)d * (DQ * 4) + c * 4;
    atomicAdd(hp + 0, v.x);
    atomicAdd(hp + 1, v.y);
    atomicAdd(hp + 2, v.z);
    atomicAdd(hp + 3, v.w);
}

__global__ __launch_bounds__(256)
void fill_zero4(float4* __restrict__ p, int n4)
{
    int i = blockIdx.x * 256 + threadIdx.x;
    if (i < n4) p[i] = make_float4(0.f, 0.f, 0.f, 0.f);
}

__global__ __launch_bounds__(256)
void combine_avg(const float* __restrict__ a, const float* __restrict__ b,
                 float* __restrict__ o, int n4)
{
    int i = blockIdx.x * 256 + threadIdx.x;
    if (i >= n4) return;
    float4 x = ((const float4*)a)[i], y = ((const float4*)b)[i];
    ((float4*)o)[i] = make_float4(0.5f * (x.x + y.x), 0.5f * (x.y + y.y),
                                  0.5f * (x.z + y.z), 0.5f * (x.w + y.w));
}

extern "C" void kernel_launch(void* const* d_in, const int* in_sizes, int n_in,
                              void* d_out, int out_size, void* d_ws, size_t ws_size,
                              hipStream_t stream)
{
    const float* v_feat = (const float*)d_in[0];
    const float* t_feat = (const float*)d_in[1];
    const float* id_emb = (const float*)d_in[2];
    const int*   edge   = (const int*)d_in[3];
    const int nE = in_sizes[3] / 2;            // 500000 directed edges
    const int* src = edge;
    const int* dst = edge + nE;

    // Workspace layout (floats)
    float* ws = (float*)d_ws;
    float* X   = ws;                            // [N,256]
    float* Mb  = X   + (size_t)NC * 256;        // [N,256]
    float* Hb  = Mb  + (size_t)NC * 256;        // [N,256]
    float* XH  = Hb  + (size_t)NC * 256;        // [N,64]
    float* Xc  = XH  + (size_t)NC * 64;         // [N,64]
    float* Vo  = Xc  + (size_t)NC * 64;         // [N,64]

    const int gM_N  = (NC + 63) / 64;           // 1563
    const int gM_NI = (NIC + 63) / 64;          // 938

    for (int p = 0; p < 2; ++p) {
        const int base = 4 + 18 * p;
        const float* feat  = p == 0 ? v_feat : t_feat;
        const int    FD    = in_sizes[p] / NIC;            // 2048 / 768
        const float* pref  = (const float*)d_in[base + 0];
        const float* mlp_w = (const float*)d_in[base + 1];
        const float* mlp_b = (const float*)d_in[base + 2];
        const float* conv_w[3] = {(const float*)d_in[base + 3],
                                  (const float*)d_in[base + 4],
                                  (const float*)d_in[base + 5]};
        const float* lin_w[3]  = {(const float*)d_in[base + 6],
                                  (const float*)d_in[base + 8],
                                  (const float*)d_in[base + 10]};
        const float* lin_b[3]  = {(const float*)d_in[base + 7],
                                  (const float*)d_in[base + 9],
                                  (const float*)d_in[base + 11]};
        const float* g_w[3]    = {(const float*)d_in[base + 12],
                                  (const float*)d_in[base + 14],
                                  (const float*)d_in[base + 16]};
        const float* g_b[3]    = {(const float*)d_in[base + 13],
                                  (const float*)d_in[base + 15],
                                  (const float*)d_in[base + 17]};

        // x = l2norm(cat(pref, feat @ mlp_w + mlp_b))
        gemm_f32<EPI_BIAS, false><<<dim3(gM_NI, 4), 256, 0, stream>>>(
            feat, mlp_w, mlp_b, nullptr, X + (size_t)NUC * 256, NIC, FD, 256);
        build_norm_x<<<NC / 4, 256, 0, stream>>>(pref, X, NUC, NC);

        // ---- layer 1 (DL=256 -> DX=64) ----
        fill_zero4<<<(NC * 256 / 4 + 255) / 256, 256, 0, stream>>>((float4*)Hb, NC * 256 / 4);
        gemm_f32<EPI_NONE, false><<<dim3(gM_N, 4), 256, 0, stream>>>(
            X, conv_w[0], nullptr, nullptr, Mb, NC, 256, 256);
        scatter_add<64><<<(nE * 64 + 255) / 256, 256, 0, stream>>>(Mb, src, dst, Hb, nE);
        gemm_f32<EPI_LIN, false><<<dim3(gM_N, 1), 256, 0, stream>>>(
            X, lin_w[0], lin_b[0], id_emb, XH, NC, 256, 64);
        gemm_f32<EPI_G, true><<<dim3(gM_N, 1), 256, 0, stream>>>(
            Hb, g_w[0], g_b[0], XH, Xc, NC, 256, 64);

        // ---- layers 2,3 (DX=64 -> DX=64) ----
        for (int l = 1; l < 3; ++l) {
            fill_zero4<<<(NC * 64 / 4 + 255) / 256, 256, 0, stream>>>((float4*)Hb, NC * 64 / 4);
            gemm_f32<EPI_NONE, false><<<dim3(gM_N, 1), 256, 0, stream>>>(
                Xc, conv_w[l], nullptr, nullptr, Mb, NC, 64, 64);
            scatter_add<16><<<(nE * 16 + 255) / 256, 256, 0, stream>>>(Mb, src, dst, Hb, nE);
            gemm_f32<EPI_LIN, false><<<dim3(gM_N, 1), 256, 0, stream>>>(
                Xc, lin_w[l], lin_b[l], id_emb, XH, NC, 64, 64);
            float* dest = (l == 2 && p == 0) ? Vo : Xc;
            gemm_f32<EPI_G, true><<<dim3(gM_N, 1), 256, 0, stream>>>(
                Hb, g_w[l], g_b[l], XH, dest, NC, 64, 64);
        }
    }

    // out = (v + t) / 2
    combine_avg<<<(NC * 64 / 4 + 255) / 256, 256, 0, stream>>>(
        Vo, Xc, (float*)d_out, NC * 64 / 4);
}

// Round 2
// 2647.802 us; speedup vs baseline: 2.7454x; 2.7454x over previous
//
#include <hip/hip_runtime.h>
#include <cstddef>

// Problem constants (match reference)
#define NUC 40000
#define NIC 60000
#define NC  100000   // NU + NI
#define DLC 256
#define DXC 64

__device__ __forceinline__ float lrelu(float x) { return x >= 0.f ? x : 0.01f * x; }

enum { EPI_NONE = 0, EPI_BIAS = 1, EPI_LIN = 2, EPI_G = 3 };

// C[M,Nc] = epi( op(A[M,K]) @ W[K,Nc] )
template<int EPI, bool LRELU_A>
__global__ __launch_bounds__(256)
void gemm_f32(const float* __restrict__ A, const float* __restrict__ W,
              const float* __restrict__ bias, const float* __restrict__ extra,
              float* __restrict__ C, int M, int K, int Nc)
{
    __shared__ float As[16][68];
    __shared__ float Bs[16][68];

    const int t    = threadIdx.x;
    const int row0 = blockIdx.x * 64;
    const int n0   = blockIdx.y * 64;
    const int tm   = t >> 4;
    const int tn   = t & 15;
    const int ak   = t & 15;
    const int am   = t >> 4;
    const int bn   = t & 63;
    const int bk0  = t >> 6;

    float acc[4][4] = {};

    for (int k0 = 0; k0 < K; k0 += 16) {
        #pragma unroll
        for (int i = 0; i < 4; ++i) {
            int m = am + 16 * i;
            int r = row0 + m;
            float v = (r < M) ? A[(size_t)r * K + k0 + ak] : 0.f;
            if constexpr (LRELU_A) v = lrelu(v);
            As[ak][m] = v;
        }
        #pragma unroll
        for (int j = 0; j < 4; ++j) {
            int k = bk0 + 4 * j;
            Bs[k][bn] = W[(size_t)(k0 + k) * Nc + n0 + bn];
        }
        __syncthreads();
        #pragma unroll
        for (int kk = 0; kk < 16; ++kk) {
            float4 a4 = *(const float4*)&As[kk][tm << 2];
            float4 b4 = *(const float4*)&Bs[kk][tn << 2];
            float av[4] = {a4.x, a4.y, a4.z, a4.w};
            float bv[4] = {b4.x, b4.y, b4.z, b4.w};
            #pragma unroll
            for (int i = 0; i < 4; ++i)
                #pragma unroll
                for (int j = 0; j < 4; ++j)
                    acc[i][j] = fmaf(av[i], bv[j], acc[i][j]);
        }
        __syncthreads();
    }

    #pragma unroll
    for (int i = 0; i < 4; ++i) {
        int r = row0 + (tm << 2) + i;
        if (r >= M) continue;
        float o[4];
        #pragma unroll
        for (int j = 0; j < 4; ++j) {
            int cn = n0 + (tn << 2) + j;
            float v = acc[i][j];
            if constexpr (EPI == EPI_BIAS) {
                v += bias[cn];
            } else if constexpr (EPI == EPI_LIN) {
                v = lrelu(v + bias[cn]) + extra[(size_t)r * Nc + cn];
            } else if constexpr (EPI == EPI_G) {
                v = lrelu(v + bias[cn] + extra[(size_t)r * Nc + cn]);
            }
            o[j] = v;
        }
        *(float4*)&C[(size_t)r * Nc + n0 + (tn << 2)] =
            make_float4(o[0], o[1], o[2], o[3]);
    }
}

// x[row] = (row < NU ? pref[row] : x[row]) / max(||.||2, 1e-12); one wave per row
__global__ __launch_bounds__(256)
void build_norm_x(const float* __restrict__ pref, float* __restrict__ x, int nu, int n)
{
    int row  = blockIdx.x * 4 + (threadIdx.x >> 6);
    int lane = threadIdx.x & 63;
    if (row >= n) return;
    const float* srcp = (row < nu) ? (pref + (size_t)row * 256) : (x + (size_t)row * 256);
    float4 v = ((const float4*)srcp)[lane];
    float s = v.x * v.x + v.y * v.y + v.z * v.z + v.w * v.w;
    #pragma unroll
    for (int off = 32; off; off >>= 1) s += __shfl_xor(s, off);
    float scale = 1.f / fmaxf(sqrtf(s), 1e-12f);
    v.x *= scale; v.y *= scale; v.z *= scale; v.w *= scale;
    ((float4*)(x + (size_t)row * 256))[lane] = v;
}

// ---------------- CSR build (once per launch) ----------------

__global__ __launch_bounds__(256)
void zero_int(int* __restrict__ p, int n)
{
    int i = blockIdx.x * 256 + threadIdx.x;
    if (i < n) p[i] = 0;
}

__global__ __launch_bounds__(256)
void hist_dst(const int* __restrict__ dst, int* __restrict__ deg, int nE)
{
    int e = blockIdx.x * 256 + threadIdx.x;
    if (e < nE) atomicAdd(&deg[dst[e]], 1);
}

// per-chunk exclusive scan (1024 elems per block), chunk total to bsum
__global__ __launch_bounds__(256)
void scan_local(const int* __restrict__ deg, int* __restrict__ tmp,
                int* __restrict__ bsum, int n)
{
    __shared__ int s[256];
    int b = blockIdx.x, t = threadIdx.x;
    int base = b * 1024 + t * 4;
    int v[4];
    #pragma unroll
    for (int j = 0; j < 4; ++j) v[j] = (base + j < n) ? deg[base + j] : 0;
    int tsum = v[0] + v[1] + v[2] + v[3];
    s[t] = tsum;
    __syncthreads();
    for (int off = 1; off < 256; off <<= 1) {
        int x = (t >= off) ? s[t - off] : 0;
        __syncthreads();
        s[t] += x;
        __syncthreads();
    }
    int run = s[t] - tsum;   // exclusive prefix of this thread within chunk
    #pragma unroll
    for (int j = 0; j < 4; ++j) {
        if (base + j < n) tmp[base + j] = run;
        run += v[j];
    }
    if (t == 255) bsum[b] = s[255];
}

__global__ void scan_bsum(int* __restrict__ bsum, int nb)
{
    if (threadIdx.x == 0 && blockIdx.x == 0) {
        int run = 0;
        for (int i = 0; i < nb; ++i) { int v = bsum[i]; bsum[i] = run; run += v; }
    }
}

__global__ __launch_bounds__(256)
void add_off(const int* __restrict__ tmp, const int* __restrict__ bsum,
             int* __restrict__ rowptr, int* __restrict__ cursor, int n, int total)
{
    int i = blockIdx.x * 256 + threadIdx.x;
    if (i < n) {
        int v = tmp[i] + bsum[i >> 10];
        rowptr[i] = v;
        cursor[i] = v;
    }
    if (i == 0) rowptr[n] = total;
}

__global__ __launch_bounds__(256)
void fill_col(const int* __restrict__ src, const int* __restrict__ dst,
              int* __restrict__ cursor, int* __restrict__ col, int nE)
{
    int e = blockIdx.x * 256 + threadIdx.x;
    if (e >= nE) return;
    int p = atomicAdd(&cursor[dst[e]], 1);
    col[p] = src[e];
}

// ---------------- CSR gather aggregation ----------------

// h[row][:] = sum_{i in row bucket} m[col[i]][:], D=256 floats (float4/lane)
__global__ __launch_bounds__(256)
void gather256(const float* __restrict__ m, const int* __restrict__ rowptr,
               const int* __restrict__ col, float* __restrict__ h, int n)
{
    int row  = blockIdx.x * 4 + (threadIdx.x >> 6);
    if (row >= n) return;
    int lane = threadIdx.x & 63;
    int s0 = rowptr[row], s1 = rowptr[row + 1];
    float4 acc = make_float4(0.f, 0.f, 0.f, 0.f);
    for (int i = s0; i < s1; ++i) {
        int s = col[i];
        float4 v = *(const float4*)(m + (size_t)s * 256 + lane * 4);
        acc.x += v.x; acc.y += v.y; acc.z += v.z; acc.w += v.w;
    }
    *(float4*)(h + (size_t)row * 256 + lane * 4) = acc;
}

// D=64 floats (1 float/lane)
__global__ __launch_bounds__(256)
void gather64(const float* __restrict__ m, const int* __restrict__ rowptr,
              const int* __restrict__ col, float* __restrict__ h, int n)
{
    int row  = blockIdx.x * 4 + (threadIdx.x >> 6);
    if (row >= n) return;
    int lane = threadIdx.x & 63;
    int s0 = rowptr[row], s1 = rowptr[row + 1];
    float acc = 0.f;
    for (int i = s0; i < s1; ++i)
        acc += m[(size_t)col[i] * 64 + lane];
    h[(size_t)row * 64 + lane] = acc;
}

__global__ __launch_bounds__(256)
void combine_avg(const float* __restrict__ a, const float* __restrict__ b,
                 float* __restrict__ o, int n4)
{
    int i = blockIdx.x * 256 + threadIdx.x;
    if (i >= n4) return;
    float4 x = ((const float4*)a)[i], y = ((const float4*)b)[i];
    ((float4*)o)[i] = make_float4(0.5f * (x.x + y.x), 0.5f * (x.y + y.y),
                                  0.5f * (x.z + y.z), 0.5f * (x.w + y.w));
}

extern "C" void kernel_launch(void* const* d_in, const int* in_sizes, int n_in,
                              void* d_out, int out_size, void* d_ws, size_t ws_size,
                              hipStream_t stream)
{
    const float* v_feat = (const float*)d_in[0];
    const float* t_feat = (const float*)d_in[1];
    const float* id_emb = (const float*)d_in[2];
    const int*   edge   = (const int*)d_in[3];
    const int nE = in_sizes[3] / 2;            // 500000 directed edges
    const int* src = edge;
    const int* dst = edge + nE;

    // Workspace layout (floats)
    float* ws = (float*)d_ws;
    float* X   = ws;                            // [N,256]
    float* Mb  = X   + (size_t)NC * 256;        // [N,256]
    float* Hb  = Mb  + (size_t)NC * 256;        // [N,256]
    float* XH  = Hb  + (size_t)NC * 256;        // [N,64]
    float* Xc  = XH  + (size_t)NC * 64;         // [N,64]
    float* Vo  = Xc  + (size_t)NC * 64;         // [N,64]
    int*   iw  = (int*)(Vo + (size_t)NC * 64);  // int workspace
    int*   deg    = iw;                         // [N]
    int*   tmp    = deg    + NC;                // [N]
    int*   rowptr = tmp    + NC;                // [N+1]
    int*   cursor = rowptr + NC + 1;            // [N]
    int*   bsum   = cursor + NC;                // [nchunks]
    int*   col    = bsum   + 256;               // [2E]

    const int gM_N  = (NC + 63) / 64;           // 1563
    const int gM_NI = (NIC + 63) / 64;          // 938
    const int nchunks = (NC + 1023) / 1024;     // 98

    // ---- Build CSR (dst -> list of src), reused by all 6 aggregations ----
    zero_int<<<(NC + 255) / 256, 256, 0, stream>>>(deg, NC);
    hist_dst<<<(nE + 255) / 256, 256, 0, stream>>>(dst, deg, nE);
    scan_local<<<nchunks, 256, 0, stream>>>(deg, tmp, bsum, NC);
    scan_bsum<<<1, 64, 0, stream>>>(bsum, nchunks);
    add_off<<<(NC + 255) / 256, 256, 0, stream>>>(tmp, bsum, rowptr, cursor, NC, nE);
    fill_col<<<(nE + 255) / 256, 256, 0, stream>>>(src, dst, cursor, col, nE);

    for (int p = 0; p < 2; ++p) {
        const int base = 4 + 18 * p;
        const float* feat  = p == 0 ? v_feat : t_feat;
        const int    FD    = in_sizes[p] / NIC;            // 2048 / 768
        const float* pref  = (const float*)d_in[base + 0];
        const float* mlp_w = (const float*)d_in[base + 1];
        const float* mlp_b = (const float*)d_in[base + 2];
        const float* conv_w[3] = {(const float*)d_in[base + 3],
                                  (const float*)d_in[base + 4],
                                  (const float*)d_in[base + 5]};
        const float* lin_w[3]  = {(const float*)d_in[base + 6],
                                  (const float*)d_in[base + 8],
                                  (const float*)d_in[base + 10]};
        const float* lin_b[3]  = {(const float*)d_in[base + 7],
                                  (const float*)d_in[base + 9],
                                  (const float*)d_in[base + 11]};
        const float* g_w[3]    = {(const float*)d_in[base + 12],
                                  (const float*)d_in[base + 14],
                                  (const float*)d_in[base + 16]};
        const float* g_b[3]    = {(const float*)d_in[base + 13],
                                  (const float*)d_in[base + 15],
                                  (const float*)d_in[base + 17]};

        // x = l2norm(cat(pref, feat @ mlp_w + mlp_b))
        gemm_f32<EPI_BIAS, false><<<dim3(gM_NI, 4), 256, 0, stream>>>(
            feat, mlp_w, mlp_b, nullptr, X + (size_t)NUC * 256, NIC, FD, 256);
        build_norm_x<<<NC / 4, 256, 0, stream>>>(pref, X, NUC, NC);

        // ---- layer 1 (DL=256 -> DX=64) ----
        gemm_f32<EPI_NONE, false><<<dim3(gM_N, 4), 256, 0, stream>>>(
            X, conv_w[0], nullptr, nullptr, Mb, NC, 256, 256);
        gather256<<<(NC + 3) / 4, 256, 0, stream>>>(Mb, rowptr, col, Hb, NC);
        gemm_f32<EPI_LIN, false><<<dim3(gM_N, 1), 256, 0, stream>>>(
            X, lin_w[0], lin_b[0], id_emb, XH, NC, 256, 64);
        gemm_f32<EPI_G, true><<<dim3(gM_N, 1), 256, 0, stream>>>(
            Hb, g_w[0], g_b[0], XH, Xc, NC, 256, 64);

        // ---- layers 2,3 (DX=64 -> DX=64) ----
        for (int l = 1; l < 3; ++l) {
            gemm_f32<EPI_NONE, false><<<dim3(gM_N, 1), 256, 0, stream>>>(
                Xc, conv_w[l], nullptr, nullptr, Mb, NC, 64, 64);
            gather64<<<(NC + 3) / 4, 256, 0, stream>>>(Mb, rowptr, col, Hb, NC);
            gemm_f32<EPI_LIN, false><<<dim3(gM_N, 1), 256, 0, stream>>>(
                Xc, lin_w[l], lin_b[l], id_emb, XH, NC, 64, 64);
            float* dest = (l == 2 && p == 0) ? Vo : Xc;
            gemm_f32<EPI_G, true><<<dim3(gM_N, 1), 256, 0, stream>>>(
                Hb, g_w[l], g_b[l], XH, dest, NC, 64, 64);
        }
    }

    // out = (v + t) / 2
    combine_avg<<<(NC * 64 / 4 + 255) / 256, 256, 0, stream>>>(
        Vo, Xc, (float*)d_out, NC * 64 / 4);
}

// Round 3
// 1235.064 us; speedup vs baseline: 5.8858x; 2.1439x over previous
//
#include <hip/hip_runtime.h>
#include <cstddef>
#include <cstdint>

#define NUC 40000
#define NIC 60000
#define NC  100000

typedef short  short8 __attribute__((ext_vector_type(8)));
typedef float  f32x4  __attribute__((ext_vector_type(4)));

__device__ __forceinline__ float lrelu(float x) { return x >= 0.f ? x : 0.01f * x; }

__device__ __forceinline__ unsigned short f2bf(float f) {
    unsigned int u = __builtin_bit_cast(unsigned int, f);
    u += 0x7fffu + ((u >> 16) & 1u);           // RNE
    return (unsigned short)(u >> 16);
}
__device__ __forceinline__ float bf2f(unsigned int us) {
    return __builtin_bit_cast(float, us << 16);
}

enum { EPI_NONE = 0, EPI_BIAS = 1, EPI_LIN = 2, EPI_G = 3 };

// C[M,BN] = epi( A[M,K] @ W[K,BN] ), MFMA 16x16x32 bf16.
// WN=4: block 64x256 (waves side-by-side in N). WN=1: block 256x64 (stacked in M).
// Wt is pre-converted bf16, transposed: Wt[n][k], n in [0,BN), k in [0,K).
template<int EPI, bool A_BF16, bool OUT_BF16, int WN>
__global__ __launch_bounds__(256)
void gemm_mfma(const void* __restrict__ Av, const unsigned short* __restrict__ Wt,
               const float* __restrict__ bias, const float* __restrict__ extra,
               void* __restrict__ Cv, int M, int K)
{
    constexpr int BM  = (WN == 4) ? 64 : 256;
    constexpr int BN  = WN * 64;
    constexpr int NcC = BN;
    __shared__ __align__(16) unsigned short Al[BM][40];   // [row][k], pad 32->40
    __shared__ __align__(16) unsigned short Bl[BN][40];   // [col][k]

    const int t    = threadIdx.x;
    const int wave = t >> 6, lane = t & 63;
    const int wm   = (WN == 4) ? 0 : wave;
    const int wn   = (WN == 4) ? wave : 0;
    const int row0 = blockIdx.x * BM;
    const int fr   = lane & 15, fk = lane >> 4;

    const float*          Af = (const float*)Av;
    const unsigned short* Ab = (const unsigned short*)Av;

    f32x4 acc[4][4] = {};

    for (int k0 = 0; k0 < K; k0 += 32) {
        // ---- stage A tile (BM x 32) ----
        if constexpr (A_BF16) {
            constexpr int CPT = BM * 4 / 256;       // 16B chunks per thread
            #pragma unroll
            for (int q = 0; q < CPT; ++q) {
                int idx = q * 256 + t;
                int r = idx >> 2, ck = idx & 3;
                uint4 v = make_uint4(0, 0, 0, 0);
                if (row0 + r < M)
                    v = *(const uint4*)&Ab[(size_t)(row0 + r) * K + k0 + ck * 8];
                *(uint4*)&Al[r][ck * 8] = v;
            }
        } else {
            constexpr int CPT = BM * 8 / 256;       // float4 chunks per thread
            #pragma unroll
            for (int q = 0; q < CPT; ++q) {
                int idx = q * 256 + t;
                int r = idx >> 3, cf = idx & 7;
                float4 v = make_float4(0.f, 0.f, 0.f, 0.f);
                if (row0 + r < M)
                    v = *(const float4*)&Af[(size_t)(row0 + r) * K + k0 + cf * 4];
                uint2 pk;
                pk.x = (unsigned)f2bf(v.x) | ((unsigned)f2bf(v.y) << 16);
                pk.y = (unsigned)f2bf(v.z) | ((unsigned)f2bf(v.w) << 16);
                *(uint2*)&Al[r][cf * 4] = pk;
            }
        }
        // ---- stage B tile (BN x 32) from transposed bf16 weights ----
        {
            constexpr int CPT = BN * 4 / 256;
            #pragma unroll
            for (int q = 0; q < CPT; ++q) {
                int idx = q * 256 + t;
                int c = idx >> 2, ck = idx & 3;
                uint4 w = *(const uint4*)&Wt[(size_t)c * K + k0 + ck * 8];
                *(uint4*)&Bl[c][ck * 8] = w;
            }
        }
        __syncthreads();

        short8 a[4], b[4];
        #pragma unroll
        for (int i = 0; i < 4; ++i) a[i] = *(const short8*)&Al[wm * 64 + i * 16 + fr][fk * 8];
        #pragma unroll
        for (int n = 0; n < 4; ++n) b[n] = *(const short8*)&Bl[wn * 64 + n * 16 + fr][fk * 8];
        #pragma unroll
        for (int i = 0; i < 4; ++i)
            #pragma unroll
            for (int n = 0; n < 4; ++n)
                acc[i][n] = __builtin_amdgcn_mfma_f32_16x16x32_bf16(a[i], b[n], acc[i][n], 0, 0, 0);
        __syncthreads();
    }

    float*          Cf = (float*)Cv;
    unsigned short* Cb = (unsigned short*)Cv;
    #pragma unroll
    for (int i = 0; i < 4; ++i) {
        #pragma unroll
        for (int q = 0; q < 4; ++q) {
            int r = row0 + wm * 64 + i * 16 + fk * 4 + q;
            if (r >= M) continue;
            #pragma unroll
            for (int n = 0; n < 4; ++n) {
                int c = wn * 64 + n * 16 + fr;
                float v = acc[i][n][q];
                if constexpr (EPI == EPI_BIAS) v += bias[c];
                else if constexpr (EPI == EPI_LIN)
                    v = lrelu(v + bias[c]) + extra[(size_t)r * NcC + c];
                else if constexpr (EPI == EPI_G)
                    v = lrelu(v + bias[c] + extra[(size_t)r * NcC + c]);
                if constexpr (OUT_BF16) Cb[(size_t)r * NcC + c] = f2bf(v);
                else                    Cf[(size_t)r * NcC + c] = v;
            }
        }
    }
}

// ---------------- weight pre-convert (f32 [K][Nc] -> bf16 transposed [Nc][K]) ----------------

struct WtJob  { const float* w; unsigned short* wt; int K; int Nc; };
struct WtJobs { WtJob j[20]; };

__global__ __launch_bounds__(256)
void convert_wt(WtJobs jobs)
{
    WtJob jb = jobs.j[blockIdx.y];
    int n = jb.K * jb.Nc;
    int i = blockIdx.x * 256 + threadIdx.x;
    if (i >= n) return;
    int c = i / jb.K, k = i - c * jb.K;
    jb.wt[i] = f2bf(jb.w[(size_t)k * jb.Nc + c]);
}

// x[row] = (row < NU ? pref[row] : x[row]) / max(||.||2, 1e-12); one wave per row
__global__ __launch_bounds__(256)
void build_norm_x(const float* __restrict__ pref, float* __restrict__ x, int nu, int n)
{
    int row  = blockIdx.x * 4 + (threadIdx.x >> 6);
    int lane = threadIdx.x & 63;
    if (row >= n) return;
    const float* srcp = (row < nu) ? (pref + (size_t)row * 256) : (x + (size_t)row * 256);
    float4 v = ((const float4*)srcp)[lane];
    float s = v.x * v.x + v.y * v.y + v.z * v.z + v.w * v.w;
    #pragma unroll
    for (int off = 32; off; off >>= 1) s += __shfl_xor(s, off);
    float scale = 1.f / fmaxf(sqrtf(s), 1e-12f);
    v.x *= scale; v.y *= scale; v.z *= scale; v.w *= scale;
    ((float4*)(x + (size_t)row * 256))[lane] = v;
}

// ---------------- CSR build ----------------

__global__ __launch_bounds__(256)
void zero_int(int* __restrict__ p, int n)
{
    int i = blockIdx.x * 256 + threadIdx.x;
    if (i < n) p[i] = 0;
}

__global__ __launch_bounds__(256)
void hist_dst(const int* __restrict__ dst, int* __restrict__ deg, int nE)
{
    int e = blockIdx.x * 256 + threadIdx.x;
    if (e < nE) atomicAdd(&deg[dst[e]], 1);
}

__global__ __launch_bounds__(256)
void scan_local(const int* __restrict__ deg, int* __restrict__ tmp,
                int* __restrict__ bsum, int n)
{
    __shared__ int s[256];
    int b = blockIdx.x, t = threadIdx.x;
    int base = b * 1024 + t * 4;
    int v[4];
    #pragma unroll
    for (int j = 0; j < 4; ++j) v[j] = (base + j < n) ? deg[base + j] : 0;
    int tsum = v[0] + v[1] + v[2] + v[3];
    s[t] = tsum;
    __syncthreads();
    for (int off = 1; off < 256; off <<= 1) {
        int x = (t >= off) ? s[t - off] : 0;
        __syncthreads();
        s[t] += x;
        __syncthreads();
    }
    int run = s[t] - tsum;
    #pragma unroll
    for (int j = 0; j < 4; ++j) {
        if (base + j < n) tmp[base + j] = run;
        run += v[j];
    }
    if (t == 255) bsum[b] = s[255];
}

__global__ void scan_bsum(int* __restrict__ bsum, int nb)
{
    if (threadIdx.x == 0 && blockIdx.x == 0) {
        int run = 0;
        for (int i = 0; i < nb; ++i) { int v = bsum[i]; bsum[i] = run; run += v; }
    }
}

__global__ __launch_bounds__(256)
void add_off(const int* __restrict__ tmp, const int* __restrict__ bsum,
             int* __restrict__ rowptr, int* __restrict__ cursor, int n, int total)
{
    int i = blockIdx.x * 256 + threadIdx.x;
    if (i < n) {
        int v = tmp[i] + bsum[i >> 10];
        rowptr[i] = v;
        cursor[i] = v;
    }
    if (i == 0) rowptr[n] = total;
}

__global__ __launch_bounds__(256)
void fill_col(const int* __restrict__ src, const int* __restrict__ dst,
              int* __restrict__ cursor, int* __restrict__ col, int nE)
{
    int e = blockIdx.x * 256 + threadIdx.x;
    if (e >= nE) return;
    int p = atomicAdd(&cursor[dst[e]], 1);
    col[p] = src[e];
}

// ---------------- gathers: h[row] = lrelu( sum m[col[i]] ), bf16 in/out ----------------

__global__ __launch_bounds__(256)
void gather256_bf16(const unsigned short* __restrict__ m, const int* __restrict__ rowptr,
                    const int* __restrict__ col, unsigned short* __restrict__ h, int n)
{
    int row  = blockIdx.x * 4 + (threadIdx.x >> 6);
    if (row >= n) return;
    int lane = threadIdx.x & 63;
    int s0 = rowptr[row], s1 = rowptr[row + 1];
    float a0 = 0.f, a1 = 0.f, a2 = 0.f, a3 = 0.f;
    for (int i = s0; i < s1; ++i) {
        int s = col[i];
        uint2 v = *(const uint2*)(m + (size_t)s * 256 + lane * 4);
        a0 += bf2f(v.x & 0xffffu); a1 += bf2f(v.x >> 16);
        a2 += bf2f(v.y & 0xffffu); a3 += bf2f(v.y >> 16);
    }
    uint2 o;
    o.x = (unsigned)f2bf(lrelu(a0)) | ((unsigned)f2bf(lrelu(a1)) << 16);
    o.y = (unsigned)f2bf(lrelu(a2)) | ((unsigned)f2bf(lrelu(a3)) << 16);
    *(uint2*)(h + (size_t)row * 256 + lane * 4) = o;
}

__global__ __launch_bounds__(256)
void gather64_bf16(const unsigned short* __restrict__ m, const int* __restrict__ rowptr,
                   const int* __restrict__ col, unsigned short* __restrict__ h, int n)
{
    int gid  = blockIdx.x * 256 + threadIdx.x;
    int row  = gid >> 5;
    if (row >= n) return;
    int c2 = gid & 31;
    int s0 = rowptr[row], s1 = rowptr[row + 1];
    float a0 = 0.f, a1 = 0.f;
    for (int i = s0; i < s1; ++i) {
        unsigned v = *(const unsigned*)(m + (size_t)col[i] * 64 + c2 * 2);
        a0 += bf2f(v & 0xffffu); a1 += bf2f(v >> 16);
    }
    unsigned o = (unsigned)f2bf(lrelu(a0)) | ((unsigned)f2bf(lrelu(a1)) << 16);
    *(unsigned*)(h + (size_t)row * 64 + c2 * 2) = o;
}

__global__ __launch_bounds__(256)
void combine_avg(const float* __restrict__ a, const float* __restrict__ b,
                 float* __restrict__ o, int n4)
{
    int i = blockIdx.x * 256 + threadIdx.x;
    if (i >= n4) return;
    float4 x = ((const float4*)a)[i], y = ((const float4*)b)[i];
    ((float4*)o)[i] = make_float4(0.5f * (x.x + y.x), 0.5f * (x.y + y.y),
                                  0.5f * (x.z + y.z), 0.5f * (x.w + y.w));
}

extern "C" void kernel_launch(void* const* d_in, const int* in_sizes, int n_in,
                              void* d_out, int out_size, void* d_ws, size_t ws_size,
                              hipStream_t stream)
{
    const float* v_feat = (const float*)d_in[0];
    const float* t_feat = (const float*)d_in[1];
    const float* id_emb = (const float*)d_in[2];
    const int*   edge   = (const int*)d_in[3];
    const int nE = in_sizes[3] / 2;
    const int* src = edge;
    const int* dst = edge + nE;

    // Workspace layout
    float* ws = (float*)d_ws;
    float* X  = ws;                               // [N,256] f32
    float* XH = X  + (size_t)NC * 256;            // [N,64]  f32
    float* Xc = XH + (size_t)NC * 64;             // [N,64]  f32
    float* Vo = Xc + (size_t)NC * 64;             // [N,64]  f32
    unsigned short* Mb = (unsigned short*)(Vo + (size_t)NC * 64);  // [N,256] bf16
    unsigned short* Hb = Mb + (size_t)NC * 256;                    // [N,256] bf16
    unsigned short* Wt = Hb + (size_t)NC * 256;                    // bf16 weights
    int* iw = (int*)(Wt + 1001472);               // int workspace (Wt arena ~967K, padded)
    int* deg    = iw;
    int* tmp    = deg    + NC;
    int* rowptr = tmp    + NC;
    int* cursor = rowptr + NC + 1;
    int* bsum   = cursor + NC;
    int* col    = bsum   + 256;

    const int nchunks = (NC + 1023) / 1024;

    // ---- pre-convert all 20 GEMM weights to bf16, transposed [Nc][K] ----
    // per-modality order: mlp, conv1, conv2, conv3, lin1, lin2, lin3, g1, g2, g3
    const int kn[10][2] = {{0, 256}, {256, 256}, {64, 64}, {64, 64}, {256, 64},
                           {64, 64}, {64, 64}, {256, 64}, {64, 64}, {64, 64}};
    const int widx[10] = {1, 3, 4, 5, 6, 8, 10, 12, 14, 16};
    WtJobs jobs;
    unsigned short* WtP[2][10];
    unsigned short* wp = Wt;
    for (int p = 0; p < 2; ++p) {
        const int base = 4 + 18 * p;
        const int FD = in_sizes[p] / NIC;          // 2048 / 768
        for (int j = 0; j < 10; ++j) {
            int K = (j == 0) ? FD : kn[j][0];
            int Nc = kn[j][1];
            jobs.j[p * 10 + j] = WtJob{(const float*)d_in[base + widx[j]], wp, K, Nc};
            WtP[p][j] = wp;
            wp += (size_t)K * Nc;
            wp = (unsigned short*)(((size_t)wp + 15) & ~(size_t)15);
        }
    }
    convert_wt<<<dim3(2048, 20), 256, 0, stream>>>(jobs);

    // ---- CSR (dst -> srcs), reused by all aggregations ----
    zero_int<<<(NC + 255) / 256, 256, 0, stream>>>(deg, NC);
    hist_dst<<<(nE + 255) / 256, 256, 0, stream>>>(dst, deg, nE);
    scan_local<<<nchunks, 256, 0, stream>>>(deg, tmp, bsum, NC);
    scan_bsum<<<1, 64, 0, stream>>>(bsum, nchunks);
    add_off<<<(NC + 255) / 256, 256, 0, stream>>>(tmp, bsum, rowptr, cursor, NC, nE);
    fill_col<<<(nE + 255) / 256, 256, 0, stream>>>(src, dst, cursor, col, nE);

    const int g64_NI  = (NIC + 63) / 64;     // 938
    const int g64_N   = (NC + 63) / 64;      // 1563
    const int g256_N  = (NC + 255) / 256;    // 391

    for (int p = 0; p < 2; ++p) {
        const int base = 4 + 18 * p;
        const float* feat  = p == 0 ? v_feat : t_feat;
        const int    FD    = in_sizes[p] / NIC;
        const float* pref  = (const float*)d_in[base + 0];
        const float* mlp_b = (const float*)d_in[base + 2];
        const float* lin_b[3] = {(const float*)d_in[base + 7],
                                 (const float*)d_in[base + 9],
                                 (const float*)d_in[base + 11]};
        const float* g_b[3]   = {(const float*)d_in[base + 13],
                                 (const float*)d_in[base + 15],
                                 (const float*)d_in[base + 17]};

        // x = l2norm(cat(pref, feat @ mlp_w + mlp_b))
        gemm_mfma<EPI_BIAS, false, false, 4><<<g64_NI, 256, 0, stream>>>(
            feat, WtP[p][0], mlp_b, nullptr, X + (size_t)NUC * 256, NIC, FD);
        build_norm_x<<<NC / 4, 256, 0, stream>>>(pref, X, NUC, NC);

        // ---- layer 1 (256 -> 64) ----
        gemm_mfma<EPI_NONE, false, true, 4><<<g64_N, 256, 0, stream>>>(
            X, WtP[p][1], nullptr, nullptr, Mb, NC, 256);
        gather256_bf16<<<(NC + 3) / 4, 256, 0, stream>>>(Mb, rowptr, col, Hb, NC);
        gemm_mfma<EPI_LIN, false, false, 1><<<g256_N, 256, 0, stream>>>(
            X, WtP[p][4], lin_b[0], id_emb, XH, NC, 256);
        gemm_mfma<EPI_G, true, false, 1><<<g256_N, 256, 0, stream>>>(
            Hb, WtP[p][7], g_b[0], XH, Xc, NC, 256);

        // ---- layers 2,3 (64 -> 64) ----
        for (int l = 1; l < 3; ++l) {
            gemm_mfma<EPI_NONE, false, true, 1><<<g256_N, 256, 0, stream>>>(
                Xc, WtP[p][1 + l], nullptr, nullptr, Mb, NC, 64);
            gather64_bf16<<<(NC * 32 + 255) / 256, 256, 0, stream>>>(Mb, rowptr, col, Hb, NC);
            gemm_mfma<EPI_LIN, false, false, 1><<<g256_N, 256, 0, stream>>>(
                Xc, WtP[p][4 + l], lin_b[l], id_emb, XH, NC, 64);
            float* dest = (l == 2 && p == 0) ? Vo : Xc;
            gemm_mfma<EPI_G, true, false, 1><<<g256_N, 256, 0, stream>>>(
                Hb, WtP[p][7 + l], g_b[l], XH, dest, NC, 64);
        }
    }

    combine_avg<<<(NC * 64 / 4 + 255) / 256, 256, 0, stream>>>(
        Vo, Xc, (float*)d_out, NC * 64 / 4);
}